// Round 3
// baseline (336.497 us; speedup 1.0000x reference)
//
#include <hip/hip_runtime.h>
#include <hip/hip_fp16.h>
#include <math.h>

// GlGraphConv: out = x@W0 + A@(x@W1) + 0.5 * f@maxpool2(x@W2) + bias
// A-mix folded into input side: xmix[b,i] = al[i]*x[b,i-1] + ar[i]*x[b,i+1]
// so out_gemm = x@W0 + xmix@W1 (single accumulator), h3 pooled lane-locally.

typedef _Float16 f16;
typedef _Float16 f16x4 __attribute__((ext_vector_type(4)));
typedef _Float16 f16x8 __attribute__((ext_vector_type(8)));
typedef float f32x4 __attribute__((ext_vector_type(4)));

// ---- workspace layout (bytes) ----
// Wt : f16[3][256][256]  (m, g, k) k-contiguous   @ 0      (393216 B)
// al : float[16]                                  @ 393216
// ar : float[16]                                  @ 393280
// f  : float[16][8]                               @ 393344
#define WS_AL 393216
#define WS_AR (393216 + 64)
#define WS_F  (393216 + 128)

#define NEG_BIG (-9e15f)

__device__ __forceinline__ void gload_lds16(const void* g, void* l) {
  __builtin_amdgcn_global_load_lds(
      (const __attribute__((address_space(1))) unsigned int*)g,
      (__attribute__((address_space(3))) unsigned int*)l, 16, 0, 0);
}

// ============================ prep kernel ============================
__global__ __launch_bounds__(256) void prep_kernel(
    const float* __restrict__ W, const float* __restrict__ MM,
    const float* __restrict__ e, const int* __restrict__ rows,
    const int* __restrict__ cols, char* __restrict__ ws)
{
  int bid = blockIdx.x;
  if (bid < 192) {
    // transpose W[m][k][g] -> Wt[m][g][k] fp16, 32x32 LDS tiles
    __shared__ float t[32][33];
    int m = bid / 64, tile = bid % 64;
    int gi = (tile / 8) * 32, ki = (tile % 8) * 32;
    int tr = threadIdx.x >> 5, tc = threadIdx.x & 31;
    const float* src = W + m * 65536;
    f16* dst = (f16*)ws + m * 65536;
#pragma unroll
    for (int i = 0; i < 4; i++)
      t[tr + 8 * i][tc] = src[(ki + tr + 8 * i) * 256 + gi + tc];
    __syncthreads();
#pragma unroll
    for (int i = 0; i < 4; i++)
      dst[(gi + tr + 8 * i) * 256 + ki + tc] = (f16)t[tc][tr + 8 * i];
  } else {
    // dense 16x16 scatter + row softmax -> al/ar ; f = softmax(MM, axis=1)
    __shared__ float Arow[16][17];
    int tid = threadIdx.x;
    if (tid < 16) {
      for (int c = 0; c < 16; c++) Arow[tid][c] = NEG_BIG;
    }
    __syncthreads();
    if (tid < 48) Arow[rows[tid]][cols[tid]] = e[tid];
    __syncthreads();
    if (tid < 16) {
      float mx = -INFINITY;
      for (int c = 0; c < 16; c++) mx = fmaxf(mx, Arow[tid][c]);
      float d = 0.f;
      for (int c = 0; c < 16; c++) d += expf(Arow[tid][c] - mx);
      // after softmax, diag is zeroed; only neighbors survive in the mix
      float al = expf(Arow[tid][(tid + 15) & 15] - mx) / d;
      float ar = expf(Arow[tid][(tid + 1) & 15] - mx) / d;
      ((float*)(ws + WS_AL))[tid] = al;
      ((float*)(ws + WS_AR))[tid] = ar;
    }
    if (tid >= 64 && tid < 80) {
      int i = tid - 64;
      float v[8];
      float mx = -INFINITY;
      for (int k = 0; k < 8; k++) { v[k] = MM[i * 8 + k]; mx = fmaxf(mx, v[k]); }
      float d = 0.f;
      for (int k = 0; k < 8; k++) d += expf(v[k] - mx);
      for (int k = 0; k < 8; k++)
        ((float*)(ws + WS_F))[i * 8 + k] = expf(v[k] - mx) / d;
    }
  }
}

// ============================ main kernel ============================
// grid: 4096 = 2048 row-tiles (64 rows = 4 batches) x 2 g-tiles (128)
// block: 256 thr = 4 waves; wave w owns rows 0..63 x g [w*32, w*32+32)
// LDS stage: xs f16[64][32] @0, xm @4096, wl f16[3][128][32] @8192 (32768 B)
//   -> unpadded stride 64B: frag b128 reads are contiguous 1024B per wave
//   -> wl layout order == global_load_lds linear lane order (base + lane*16)
// LDS epi  : h3p f32[4][8][130] @0 (16640 B, overlaps stage region)
__global__ __launch_bounds__(256, 4) void glgc_main(
    const float* __restrict__ x, const float* __restrict__ bias,
    const char* __restrict__ ws, float* __restrict__ out)
{
  __shared__ __align__(16) char smem[32768];
  f16* xs = (f16*)smem;            // [64][32]
  f16* xm = (f16*)(smem + 4096);   // [64][32]
  f16* wl = (f16*)(smem + 8192);   // [3][128][32]
  float* h3p = (float*)smem;       // [4][8][130]

  const f16* Wt = (const f16*)ws;
  const float* alf = (const float*)(ws + WS_AL);
  const float* arf = (const float*)(ws + WS_AR);
  const float* fm  = (const float*)(ws + WS_F);

  int bid = blockIdx.x;
  int gt = bid & 1, bt = bid >> 1;
  int row0 = bt * 64;   // global row = b*16 + joint
  int g0 = gt * 128;

  int tid = threadIdx.x;
  int w = tid >> 6, lane = tid & 63;
  int lg = lane >> 4, lc = lane & 15;

  // ---- x staging map: thread -> row sr = tid>>2, k-quarter sq = tid&3 ----
  int sr = tid >> 2, sq = tid & 3;
  int si = sr & 15;
  int rp = (sr & ~15) | ((si + 15) & 15);
  int rn = (sr & ~15) | ((si + 1) & 15);
  float al_i = alf[si], ar_i = arf[si];
  const float* xg  = x + (row0 + sr) * 256 + sq * 8;
  const float* xgp = x + (row0 + rp) * 256 + sq * 8;
  const float* xgn = x + (row0 + rn) * 256 + sq * 8;
  f16* xs_w = xs + tid * 8;   // byte tid*16: contiguous per wave
  f16* xm_w = xm + tid * 8;

  // ---- W staging map: idx = tid + t*256 -> (m, g, k8); dest = idx*16B ----
  const f16* wsrc[6];
  f16* wdst[6];
#pragma unroll
  for (int t = 0; t < 6; t++) {
    int idx = tid + t * 256;
    int m = idx >> 9, rem = idx & 511;
    int g = rem >> 2, k8 = rem & 3;
    wsrc[t] = Wt + (m << 16) + (g0 + g) * 256 + k8 * 8;
    wdst[t] = wl + idx * 8;
  }

  // ---- fragment read bases (unpadded: contiguous 1024B wave reads) ----
  const f16* xs_r = xs + lc * 32 + lg * 8;
  const f16* xm_r = xm + lc * 32 + lg * 8;
  const f16* wb_r = wl + (w * 32 + lc) * 32 + lg * 8;

  f32x4 accO[4][2] = {};  // x@W0 + xmix@W1
  f32x4 accH[4][2] = {};  // x@W2

#pragma unroll
  for (int kc = 0; kc < 8; kc++) {
    int k0 = kc * 32;
    __syncthreads();
    // ---- async W -> LDS (no VGPR round trip) ----
#pragma unroll
    for (int t = 0; t < 6; t++)
      gload_lds16(wsrc[t] + k0, wdst[t]);
    // ---- stage x and xmix (fp32 -> fp16, mix coeffs applied in fp32) ----
    {
      float4 v0 = *(const float4*)(xg + k0);
      float4 v1 = *(const float4*)(xg + k0 + 4);
      float4 p0 = *(const float4*)(xgp + k0);
      float4 p1 = *(const float4*)(xgp + k0 + 4);
      float4 n0 = *(const float4*)(xgn + k0);
      float4 n1 = *(const float4*)(xgn + k0 + 4);
      f16x8 sv = {(f16)v0.x, (f16)v0.y, (f16)v0.z, (f16)v0.w,
                  (f16)v1.x, (f16)v1.y, (f16)v1.z, (f16)v1.w};
      f16x8 mv = {(f16)(al_i * p0.x + ar_i * n0.x),
                  (f16)(al_i * p0.y + ar_i * n0.y),
                  (f16)(al_i * p0.z + ar_i * n0.z),
                  (f16)(al_i * p0.w + ar_i * n0.w),
                  (f16)(al_i * p1.x + ar_i * n1.x),
                  (f16)(al_i * p1.y + ar_i * n1.y),
                  (f16)(al_i * p1.z + ar_i * n1.z),
                  (f16)(al_i * p1.w + ar_i * n1.w)};
      *(f16x8*)xs_w = sv;
      *(f16x8*)xm_w = mv;
    }
    __syncthreads();
    // ---- fragments ----
    f16x8 xa[4], xma[4];
#pragma unroll
    for (int m = 0; m < 4; m++) {
      xa[m]  = *(const f16x8*)(xs_r + m * 512);
      xma[m] = *(const f16x8*)(xm_r + m * 512);
    }
    f16x8 wb0[2], wb1[2], wb2[2];
#pragma unroll
    for (int n = 0; n < 2; n++) {
      wb0[n] = *(const f16x8*)(wb_r + n * 512);
      wb1[n] = *(const f16x8*)(wb_r + n * 512 + 4096);
      wb2[n] = *(const f16x8*)(wb_r + n * 512 + 8192);
    }
    // ---- MFMA: 24 per chunk per wave ----
#pragma unroll
    for (int m = 0; m < 4; m++) {
#pragma unroll
      for (int n = 0; n < 2; n++) {
        accO[m][n] = __builtin_amdgcn_mfma_f32_16x16x32_f16(xa[m],  wb0[n], accO[m][n], 0, 0, 0);
        accO[m][n] = __builtin_amdgcn_mfma_f32_16x16x32_f16(xma[m], wb1[n], accO[m][n], 0, 0, 0);
        accH[m][n] = __builtin_amdgcn_mfma_f32_16x16x32_f16(xa[m],  wb2[n], accH[m][n], 0, 0, 0);
      }
    }
  }

  // ---- epilogue ----
  // maxpool pairs (lg*4+2r, lg*4+2r+1) are lane-local in the C fragment:
  // pooled row (within m-tile) = lg*2 + r
  __syncthreads();
#pragma unroll
  for (int m = 0; m < 4; m++) {
#pragma unroll
    for (int n = 0; n < 2; n++) {
      int col = w * 32 + n * 16 + lc;
      h3p[(m * 8 + lg * 2) * 130 + col]     = fmaxf(accH[m][n][0], accH[m][n][1]);
      h3p[(m * 8 + lg * 2 + 1) * 130 + col] = fmaxf(accH[m][n][2], accH[m][n][3]);
    }
  }
  __syncthreads();

  float fc[4][8];
#pragma unroll
  for (int r = 0; r < 4; r++)
#pragma unroll
    for (int k = 0; k < 8; k++)
      fc[r][k] = fm[(lg * 4 + r) * 8 + k];
  float b0 = bias[g0 + w * 32 + lc];
  float b1 = bias[g0 + w * 32 + 16 + lc];

#pragma unroll
  for (int m = 0; m < 4; m++) {
#pragma unroll
    for (int n = 0; n < 2; n++) {
      int col = w * 32 + n * 16 + lc;
      float p[8];
#pragma unroll
      for (int k = 0; k < 8; k++)
        p[k] = h3p[(m * 8 + k) * 130 + col];
      float bb = n ? b1 : b0;
#pragma unroll
      for (int r = 0; r < 4; r++) {
        float y1 = 0.f;
#pragma unroll
        for (int k = 0; k < 8; k++) y1 += fc[r][k] * p[k];
        int grow = row0 + m * 16 + lg * 4 + r;
        out[grow * 256 + g0 + col] = accO[m][n][r] + 0.5f * y1 + bb;
      }
    }
  }
}

// ============================ launcher ============================
extern "C" void kernel_launch(void* const* d_in, const int* in_sizes, int n_in,
                              void* d_out, int out_size, void* d_ws, size_t ws_size,
                              hipStream_t stream) {
  const float* x    = (const float*)d_in[0];
  const float* W    = (const float*)d_in[1];
  const float* MM   = (const float*)d_in[2];
  const float* e    = (const float*)d_in[3];
  const float* bias = (const float*)d_in[4];
  const int* rows   = (const int*)d_in[5];
  const int* cols   = (const int*)d_in[6];
  float* out = (float*)d_out;
  char* ws = (char*)d_ws;

  prep_kernel<<<193, 256, 0, stream>>>(W, MM, e, rows, cols, ws);
  glgc_main<<<4096, 256, 0, stream>>>(x, bias, ws, out);
}

// Round 4
// 286.889 us; speedup vs baseline: 1.1729x; 1.1729x over previous
//
#include <hip/hip_runtime.h>
#include <hip/hip_fp16.h>
#include <math.h>

// GlGraphConv: out = x@W0 + A@(x@W1) + 0.5 * f@maxpool2(x@W2) + bias
// Round-4 structure:
//   h0,h1,h3 = x@W{0,1,2} via three MFMA accumulators (no input-side fold).
//   Ring-mix A@h1 and joint-maxpool applied in epilogue via LDS exchanges.
//   x staged to LDS once per K-half; inner loop stages only W (L2-resident)
//   through global_load_lds, 2-phase double-buffered, counted vmcnt(6),
//   raw s_barrier (no full drains in the main loop).

typedef _Float16 f16;
typedef _Float16 f16x8 __attribute__((ext_vector_type(8)));
typedef float f32x4 __attribute__((ext_vector_type(4)));

// ---- workspace layout (bytes) ----
// Wt : f16[3][256][256]  (m, g, k) k-contiguous   @ 0      (393216 B)
// al : float[16] @393216 ; ar : float[16] @393280 ; f : float[16][8] @393344
#define WS_AL 393216
#define WS_AR (393216 + 64)
#define WS_F  (393216 + 128)
#define NEG_BIG (-9e15f)

__device__ __forceinline__ void gload_lds16(const void* g, void* l) {
  __builtin_amdgcn_global_load_lds(
      (const __attribute__((address_space(1))) unsigned int*)g,
      (__attribute__((address_space(3))) unsigned int*)l, 16, 0, 0);
}

// ============================ prep kernel ============================
__global__ __launch_bounds__(256) void prep_kernel(
    const float* __restrict__ W, const float* __restrict__ MM,
    const float* __restrict__ e, const int* __restrict__ rows,
    const int* __restrict__ cols, char* __restrict__ ws)
{
  int bid = blockIdx.x;
  if (bid < 192) {
    // transpose W[m][k][g] -> Wt[m][g][k] fp16, 32x32 LDS tiles
    __shared__ float t[32][33];
    int m = bid / 64, tile = bid % 64;
    int gi = (tile / 8) * 32, ki = (tile % 8) * 32;
    int tr = threadIdx.x >> 5, tc = threadIdx.x & 31;
    const float* src = W + m * 65536;
    f16* dst = (f16*)ws + m * 65536;
#pragma unroll
    for (int i = 0; i < 4; i++)
      t[tr + 8 * i][tc] = src[(ki + tr + 8 * i) * 256 + gi + tc];
    __syncthreads();
#pragma unroll
    for (int i = 0; i < 4; i++)
      dst[(gi + tr + 8 * i) * 256 + ki + tc] = (f16)t[tc][tr + 8 * i];
  } else {
    __shared__ float Arow[16][17];
    int tid = threadIdx.x;
    if (tid < 16) {
      for (int c = 0; c < 16; c++) Arow[tid][c] = NEG_BIG;
    }
    __syncthreads();
    if (tid < 48) Arow[rows[tid]][cols[tid]] = e[tid];
    __syncthreads();
    if (tid < 16) {
      float mx = -INFINITY;
      for (int c = 0; c < 16; c++) mx = fmaxf(mx, Arow[tid][c]);
      float d = 0.f;
      for (int c = 0; c < 16; c++) d += expf(Arow[tid][c] - mx);
      // after softmax, diag is zeroed; only neighbors survive in the mix
      float al = expf(Arow[tid][(tid + 15) & 15] - mx) / d;
      float ar = expf(Arow[tid][(tid + 1) & 15] - mx) / d;
      ((float*)(ws + WS_AL))[tid] = al;
      ((float*)(ws + WS_AR))[tid] = ar;
    }
    if (tid >= 64 && tid < 80) {
      int i = tid - 64;
      float v[8];
      float mx = -INFINITY;
      for (int k = 0; k < 8; k++) { v[k] = MM[i * 8 + k]; mx = fmaxf(mx, v[k]); }
      float d = 0.f;
      for (int k = 0; k < 8; k++) d += expf(v[k] - mx);
      for (int k = 0; k < 8; k++)
        ((float*)(ws + WS_F))[i * 8 + k] = expf(v[k] - mx) / d;
    }
  }
}

// ============================ main kernel ============================
// grid: 4096 = 2048 row-tiles (64 rows = 4 batches) x 2 g-tiles (128)
// block: 256 thr = 4 waves; wave w owns rows 0..63 x g [w*32, w*32+32)
// LDS: xs 4 chunks x 4KB @0 (16KB) ; wl 2 bufs x 24KB @16384 ; = 64KB exact
//   all staging writes / frag reads are contiguous 1024B wave accesses
// epilogue reuses wl region: h1x / h3p f32 [.][132] (2-way banks = free)
__global__ __launch_bounds__(256, 2) void glgc_main(
    const float* __restrict__ x, const float* __restrict__ bias,
    const char* __restrict__ ws, float* __restrict__ out)
{
  __shared__ __align__(16) char smem[65536];

  const f16* Wt = (const f16*)ws;
  const float* alf = (const float*)(ws + WS_AL);
  const float* arf = (const float*)(ws + WS_AR);
  const float* fm  = (const float*)(ws + WS_F);

  int bid = blockIdx.x;
  int gt = bid & 1, bt = bid >> 1;
  int row0 = bt * 64;   // global row = b*16 + joint ; 64 rows = 4 full batches
  int g0 = gt * 128;

  int tid = threadIdx.x;
  int w = tid >> 6, lane = tid & 63;
  int lg = lane >> 4, lc = lane & 15;

  // x staging: thread (sr=tid>>2, sq=tid&3) owns row sr, k-window sq*8..+7
  int sr = tid >> 2, sq = tid & 3;
  const float* xrow = x + (row0 + sr) * 256 + sq * 8;

  // W staging: instr t covers idx = tid + t*256 -> (m,g,k8); dest idx*16 B
  const f16* wsrc[6];
  int wdst[6];
#pragma unroll
  for (int t = 0; t < 6; ++t) {
    int idx = tid + t * 256;
    int m = idx >> 9, rem = idx & 511;
    int g = rem >> 2, k8 = rem & 3;
    wsrc[t] = Wt + (m << 16) + (g0 + g) * 256 + k8 * 8;
    wdst[t] = 16384 + idx * 16;
  }

  f32x4 acc0[4][2] = {};  // x@W0
  f32x4 acc1[4][2] = {};  // x@W1 (h1, mixed in epilogue)
  f32x4 acc2[4][2] = {};  // x@W2 (h3, pooled in epilogue)

  // prologue: issue W chunk 0 -> buf 0 (latency hides under x-stage)
#pragma unroll
  for (int t = 0; t < 6; ++t)
    gload_lds16(wsrc[t], smem + wdst[t]);

#pragma unroll
  for (int c = 0; c < 8; ++c) {
    if ((c & 3) == 0) {
      // stage x half (c>>2): 64 rows x 128 k, fp32->fp16, chunk-major
      const float* xb = xrow + (c >> 2) * 128;
      float4 xv[8];
#pragma unroll
      for (int k2 = 0; k2 < 4; ++k2) {
        xv[2 * k2]     = *(const float4*)(xb + k2 * 32);
        xv[2 * k2 + 1] = *(const float4*)(xb + k2 * 32 + 4);
      }
#pragma unroll
      for (int k2 = 0; k2 < 4; ++k2) {
        float4 a = xv[2 * k2], b = xv[2 * k2 + 1];
        f16x8 v = {(f16)a.x, (f16)a.y, (f16)a.z, (f16)a.w,
                   (f16)b.x, (f16)b.y, (f16)b.z, (f16)b.w};
        *(f16x8*)(smem + k2 * 4096 + tid * 16) = v;
      }
      asm volatile("s_waitcnt lgkmcnt(0)" ::: "memory");
    }
    if (c < 7) {
      // prefetch W chunk c+1 into the other buffer
#pragma unroll
      for (int t = 0; t < 6; ++t)
        gload_lds16(wsrc[t] + (c + 1) * 32, smem + wdst[t] + ((c + 1) & 1) * 24576);
      asm volatile("s_waitcnt vmcnt(6)" ::: "memory");   // W(c) landed
    } else {
      asm volatile("s_waitcnt vmcnt(0)" ::: "memory");   // W(7) landed
    }
    __builtin_amdgcn_s_barrier();
    __builtin_amdgcn_sched_barrier(0);

    // fragments (contiguous 1024B wave reads, conflict-free)
    const char* xcb = smem + (c & 3) * 4096 + lc * 64 + lg * 16;
    const char* wcb = smem + 16384 + (c & 1) * 24576 + (w * 32 + lc) * 64 + lg * 16;
    f16x8 xa[4];
#pragma unroll
    for (int m = 0; m < 4; ++m) xa[m] = *(const f16x8*)(xcb + m * 1024);
    f16x8 wb0[2], wb1[2], wb2[2];
#pragma unroll
    for (int n = 0; n < 2; ++n) {
      wb0[n] = *(const f16x8*)(wcb + n * 1024);
      wb1[n] = *(const f16x8*)(wcb + n * 1024 + 8192);
      wb2[n] = *(const f16x8*)(wcb + n * 1024 + 16384);
    }
    // 24 independent MFMAs
#pragma unroll
    for (int m = 0; m < 4; ++m)
#pragma unroll
      for (int n = 0; n < 2; ++n) {
        acc0[m][n] = __builtin_amdgcn_mfma_f32_16x16x32_f16(xa[m], wb0[n], acc0[m][n], 0, 0, 0);
        acc1[m][n] = __builtin_amdgcn_mfma_f32_16x16x32_f16(xa[m], wb1[n], acc1[m][n], 0, 0, 0);
        acc2[m][n] = __builtin_amdgcn_mfma_f32_16x16x32_f16(xa[m], wb2[n], acc2[m][n], 0, 0, 0);
      }
    __builtin_amdgcn_sched_barrier(0);
    __builtin_amdgcn_s_barrier();   // buf[c&1] free for chunk c+2's prefetch
  }

  // ======================= epilogue =======================
  __syncthreads();
  float* h1x = (float*)(smem + 16384);   // [64][132] f32 (33.8KB, in wl region)
  int coln0 = w * 32 + lc, coln1 = w * 32 + 16 + lc;

  // phase 1: ring-mix of h1 (row = m*16 + joint, joint = lg*4+r, wrap mod 16)
#pragma unroll
  for (int m = 0; m < 4; ++m)
#pragma unroll
    for (int r = 0; r < 4; ++r) {
      h1x[(m * 16 + lg * 4 + r) * 132 + coln0] = acc1[m][0][r];
      h1x[(m * 16 + lg * 4 + r) * 132 + coln1] = acc1[m][1][r];
    }
  __syncthreads();
  float alv[4], arv[4];
#pragma unroll
  for (int r = 0; r < 4; ++r) {
    alv[r] = alf[lg * 4 + r];
    arv[r] = arf[lg * 4 + r];
  }
#pragma unroll
  for (int m = 0; m < 4; ++m)
#pragma unroll
    for (int r = 0; r < 4; ++r) {
      int j = lg * 4 + r;
      int jm = (j + 15) & 15, jp = (j + 1) & 15;
      acc0[m][0][r] += alv[r] * h1x[(m * 16 + jm) * 132 + coln0]
                     + arv[r] * h1x[(m * 16 + jp) * 132 + coln0];
      acc0[m][1][r] += alv[r] * h1x[(m * 16 + jm) * 132 + coln1]
                     + arv[r] * h1x[(m * 16 + jp) * 132 + coln1];
    }
  __syncthreads();

  // phase 2: maxpool h3 (pairs lane-local) + f-mix
#pragma unroll
  for (int m = 0; m < 4; ++m) {
#pragma unroll
    for (int n = 0; n < 2; ++n) {
      int col = n ? coln1 : coln0;
      h1x[(m * 8 + lg * 2) * 132 + col]     = fmaxf(acc2[m][n][0], acc2[m][n][1]);
      h1x[(m * 8 + lg * 2 + 1) * 132 + col] = fmaxf(acc2[m][n][2], acc2[m][n][3]);
    }
  }
  __syncthreads();

  float fc[4][8];
#pragma unroll
  for (int r = 0; r < 4; ++r)
#pragma unroll
    for (int k = 0; k < 8; ++k)
      fc[r][k] = fm[(lg * 4 + r) * 8 + k];
  float bv0 = bias[g0 + coln0], bv1 = bias[g0 + coln1];

#pragma unroll
  for (int m = 0; m < 4; ++m)
#pragma unroll
    for (int n = 0; n < 2; ++n) {
      int col = n ? coln1 : coln0;
      float p[8];
#pragma unroll
      for (int k = 0; k < 8; ++k) p[k] = h1x[(m * 8 + k) * 132 + col];
      float bb = n ? bv1 : bv0;
#pragma unroll
      for (int r = 0; r < 4; ++r) {
        float y1 = 0.f;
#pragma unroll
        for (int k = 0; k < 8; ++k) y1 += fc[r][k] * p[k];
        out[(row0 + m * 16 + lg * 4 + r) * 256 + g0 + col] =
            acc0[m][n][r] + 0.5f * y1 + bb;
      }
    }
}

// ============================ launcher ============================
extern "C" void kernel_launch(void* const* d_in, const int* in_sizes, int n_in,
                              void* d_out, int out_size, void* d_ws, size_t ws_size,
                              hipStream_t stream) {
  const float* x    = (const float*)d_in[0];
  const float* W    = (const float*)d_in[1];
  const float* MM   = (const float*)d_in[2];
  const float* e    = (const float*)d_in[3];
  const float* bias = (const float*)d_in[4];
  const int* rows   = (const int*)d_in[5];
  const int* cols   = (const int*)d_in[6];
  float* out = (float*)d_out;
  char* ws = (char*)d_ws;

  prep_kernel<<<193, 256, 0, stream>>>(W, MM, e, rows, cols, ws);
  glgc_main<<<4096, 256, 0, stream>>>(x, bias, ws, out);
}